// Round 1
// baseline (344.411 us; speedup 1.0000x reference)
//
#include <hip/hip_runtime.h>

// ---------- types ----------
using bf16x8 = __attribute__((ext_vector_type(8))) short;           // 8 bf16 (4 VGPR)
using u16x8  = __attribute__((ext_vector_type(8))) unsigned short;  // 16B staging
using f32x4  = __attribute__((ext_vector_type(4))) float;
using f32x4v = __attribute__((ext_vector_type(4))) float;

__device__ inline unsigned short f2bf(float f) {
  unsigned int u = __builtin_bit_cast(unsigned int, f);
  return (unsigned short)((u + 0x7fffu + ((u >> 16) & 1u)) >> 16);  // RNE
}

#define MFMA16(a, b, c) __builtin_amdgcn_mfma_f32_16x16x32_bf16((a), (b), (c), 0, 0, 0)

// Problem constants
#define LL 4096
#define NB 4
#define DD 512
#define KDIM 128

// ==========================================================================
// proj_qk: Out[b][l][128] = bf16( l2norm( X[l][b][:] @ Wk^T + bk ) )
// X rows r = l*4+b, 16384 rows. Block: 64 rows x 128 cols, 4 waves x 16 rows.
// ==========================================================================
__global__ __launch_bounds__(256) void proj_qk_kernel(
    const float* __restrict__ X, const float* __restrict__ Wk,
    const float* __restrict__ bk, unsigned short* __restrict__ Out)
{
  __shared__ char smem[49152];                       // Xs 16KB | Ws 32KB
  char* Xs = smem;
  char* Ws = smem + 16384;

  const int tid = threadIdx.x;
  const int w = tid >> 6, lane = tid & 63, lr = lane & 15, g = lane >> 4;
  const int r0 = blockIdx.x * 64;

  f32x4 acc[8];
  #pragma unroll
  for (int nt = 0; nt < 8; ++nt) acc[nt] = f32x4{0.f, 0.f, 0.f, 0.f};

  for (int kc = 0; kc < 4; ++kc) {                   // K chunks of 128
    if (kc) __syncthreads();
    // stage X chunk [64][128] f32 -> bf16, swizzled rows of 256B
    #pragma unroll
    for (int p = 0; p < 4; ++p) {
      int j = tid + p * 256;
      int row = j >> 4, e0 = (j & 15) * 8;
      const float* src = X + (size_t)(r0 + row) * DD + kc * 128 + e0;
      f32x4v f0 = *reinterpret_cast<const f32x4v*>(src);
      f32x4v f1 = *reinterpret_cast<const f32x4v*>(src + 4);
      u16x8 v;
      #pragma unroll
      for (int e = 0; e < 4; ++e) { v[e] = f2bf(f0[e]); v[e + 4] = f2bf(f1[e]); }
      *reinterpret_cast<u16x8*>(Xs + row * 256 + ((e0 * 2) ^ ((row & 7) << 4))) = v;
    }
    // stage W chunk [128][128]
    #pragma unroll
    for (int p = 0; p < 8; ++p) {
      int j = tid + p * 256;
      int n = j >> 4, e0 = (j & 15) * 8;
      const float* src = Wk + (size_t)n * DD + kc * 128 + e0;
      f32x4v f0 = *reinterpret_cast<const f32x4v*>(src);
      f32x4v f1 = *reinterpret_cast<const f32x4v*>(src + 4);
      u16x8 v;
      #pragma unroll
      for (int e = 0; e < 4; ++e) { v[e] = f2bf(f0[e]); v[e + 4] = f2bf(f1[e]); }
      *reinterpret_cast<u16x8*>(Ws + n * 256 + ((e0 * 2) ^ ((n & 7) << 4))) = v;
    }
    __syncthreads();
    const int arow = w * 16 + lr;
    #pragma unroll
    for (int ks = 0; ks < 4; ++ks) {
      int oa = (ks * 64 + g * 16) ^ ((arow & 7) << 4);
      bf16x8 a = *reinterpret_cast<const bf16x8*>(Xs + arow * 256 + oa);
      #pragma unroll
      for (int nt = 0; nt < 8; ++nt) {
        int n = nt * 16 + lr;
        int ob = (ks * 64 + g * 16) ^ ((n & 7) << 4);
        bf16x8 bb = *reinterpret_cast<const bf16x8*>(Ws + n * 256 + ob);
        acc[nt] = MFMA16(a, bb, acc[nt]);
      }
    }
  }

  // epilogue: bias, l2 normalize per row, store bf16 [b][l][c]
  float bias[8];
  #pragma unroll
  for (int nt = 0; nt < 8; ++nt) bias[nt] = bk[nt * 16 + lr];
  #pragma unroll
  for (int nt = 0; nt < 8; ++nt)
    #pragma unroll
    for (int i = 0; i < 4; ++i) acc[nt][i] += bias[nt];

  f32x4 ss = f32x4{0.f, 0.f, 0.f, 0.f};
  #pragma unroll
  for (int nt = 0; nt < 8; ++nt)
    #pragma unroll
    for (int i = 0; i < 4; ++i) ss[i] += acc[nt][i] * acc[nt][i];
  #pragma unroll
  for (int m = 1; m < 16; m <<= 1) {
    #pragma unroll
    for (int i = 0; i < 4; ++i) ss[i] += __shfl_xor(ss[i], m);
  }
  float inv[4];
  #pragma unroll
  for (int i = 0; i < 4; ++i) inv[i] = 1.0f / fmaxf(sqrtf(ss[i]), 1e-12f);

  #pragma unroll
  for (int nt = 0; nt < 8; ++nt) {
    int c = nt * 16 + lr;
    #pragma unroll
    for (int i = 0; i < 4; ++i) {
      int r = r0 + w * 16 + g * 4 + i;
      int l = r >> 2, b = r & 3;
      Out[((size_t)(b * LL + l)) * KDIM + c] = f2bf(acc[nt][i] * inv[i]);
    }
  }
}

// ==========================================================================
// proj_v: Vt[b][d][s] = bf16( value[s][b][:] @ Wv^T + bv )   (transposed store)
// Block: 256 rows x 64 cols; grid = 64 rblocks x 8 colblocks.
// ==========================================================================
__global__ __launch_bounds__(256) void proj_v_kernel(
    const float* __restrict__ X, const float* __restrict__ Wv,
    const float* __restrict__ bv, unsigned short* __restrict__ VtOut)
{
  __shared__ char smem[40960];                       // Xs 32KB | Ws 8KB ; Ts aliases Xs
  char* Xs = smem;
  char* Ws = smem + 32768;

  const int tid = threadIdx.x;
  const int w = tid >> 6, lane = tid & 63, lr = lane & 15, g = lane >> 4;
  const int rb = blockIdx.x >> 3, nb = blockIdx.x & 7;
  const int r0 = rb * 256, d0 = nb * 64;

  f32x4 acc[4][4];
  #pragma unroll
  for (int rt = 0; rt < 4; ++rt)
    #pragma unroll
    for (int nt = 0; nt < 4; ++nt) acc[rt][nt] = f32x4{0.f, 0.f, 0.f, 0.f};

  for (int kc = 0; kc < 8; ++kc) {                   // K chunks of 64
    if (kc) __syncthreads();
    // X chunk [256][64]
    #pragma unroll
    for (int p = 0; p < 8; ++p) {
      int j = tid + p * 256;
      int row = j >> 3, e0 = (j & 7) * 8;
      const float* src = X + (size_t)(r0 + row) * DD + kc * 64 + e0;
      f32x4v f0 = *reinterpret_cast<const f32x4v*>(src);
      f32x4v f1 = *reinterpret_cast<const f32x4v*>(src + 4);
      u16x8 v;
      #pragma unroll
      for (int e = 0; e < 4; ++e) { v[e] = f2bf(f0[e]); v[e + 4] = f2bf(f1[e]); }
      *reinterpret_cast<u16x8*>(Xs + row * 128 + ((e0 * 2) ^ ((row & 7) << 4))) = v;
    }
    // W chunk [64][64]
    #pragma unroll
    for (int p = 0; p < 2; ++p) {
      int j = tid + p * 256;
      int n = j >> 3, e0 = (j & 7) * 8;
      const float* src = Wv + (size_t)(d0 + n) * DD + kc * 64 + e0;
      f32x4v f0 = *reinterpret_cast<const f32x4v*>(src);
      f32x4v f1 = *reinterpret_cast<const f32x4v*>(src + 4);
      u16x8 v;
      #pragma unroll
      for (int e = 0; e < 4; ++e) { v[e] = f2bf(f0[e]); v[e + 4] = f2bf(f1[e]); }
      *reinterpret_cast<u16x8*>(Ws + n * 128 + ((e0 * 2) ^ ((n & 7) << 4))) = v;
    }
    __syncthreads();
    #pragma unroll
    for (int ks = 0; ks < 2; ++ks) {
      bf16x8 a[4];
      #pragma unroll
      for (int rt = 0; rt < 4; ++rt) {
        int arow = w * 64 + rt * 16 + lr;
        a[rt] = *reinterpret_cast<const bf16x8*>(
            Xs + arow * 128 + ((ks * 64 + g * 16) ^ ((arow & 7) << 4)));
      }
      #pragma unroll
      for (int nt = 0; nt < 4; ++nt) {
        int n = nt * 16 + lr;
        bf16x8 bb = *reinterpret_cast<const bf16x8*>(
            Ws + n * 128 + ((ks * 64 + g * 16) ^ ((n & 7) << 4)));
        #pragma unroll
        for (int rt = 0; rt < 4; ++rt) acc[rt][nt] = MFMA16(a[rt], bb, acc[rt][nt]);
      }
    }
  }

  __syncthreads();                                   // done with Xs; reuse as Ts
  float bias[4];
  #pragma unroll
  for (int nt = 0; nt < 4; ++nt) bias[nt] = bv[d0 + nt * 16 + lr];

  unsigned short* Ts = (unsigned short*)smem;        // [64 d][256 r] u16, col-swizzled
  #pragma unroll
  for (int rt = 0; rt < 4; ++rt)
    #pragma unroll
    for (int nt = 0; nt < 4; ++nt) {
      int dl = nt * 16 + lr;
      #pragma unroll
      for (int i = 0; i < 4; ++i) {
        int rl = w * 64 + rt * 16 + g * 4 + i;
        Ts[dl * 256 + (rl ^ ((dl & 31) << 1))] = f2bf(acc[rt][nt][i] + bias[nt]);
      }
    }
  __syncthreads();

  // coalesced transposed store: thread -> (b, d), writes 64 l-contiguous bf16
  int bsel = tid >> 6, dl = tid & 63;
  int l0 = r0 >> 2;
  #pragma unroll
  for (int jj = 0; jj < 8; ++jj) {
    u16x8 v;
    #pragma unroll
    for (int e = 0; e < 8; ++e) {
      int rl = (jj * 8 + e) * 4 + bsel;
      v[e] = Ts[dl * 256 + (rl ^ ((dl & 31) << 1))];
    }
    *reinterpret_cast<u16x8*>(VtOut + ((size_t)(bsel * DD + d0 + dl)) * LL + l0 + jj * 8) = v;
  }
}

// ==========================================================================
// attn: out[q][b][d] = softmax_s(30 * <Qn[q], Kn[s]>) @ V
// grid 256 = 4 batches x 64 q-tiles(64). Block 256 thr / 4 waves.
// Wave w: S-phase for q-rows w*16..+15; PV-phase for D-slice w*128..+127 of all 64 q.
// Fixed-max softmax: p = exp2(dot*30*log2e - 31*log2e); divide by row-sum at end.
// ==========================================================================
#define QBLK 64
#define KBLK 32
#define NIT (LL / KBLK)

__global__ __launch_bounds__(256) void attn_kernel(
    const unsigned short* __restrict__ Qn, const unsigned short* __restrict__ Kn,
    const unsigned short* __restrict__ Vt, float* __restrict__ Out)
{
  __shared__ char smem[45312];
  char* Ks = smem;                                   // [32 s][128 k] bf16, 8KB
  char* Vs = smem + 8192;                            // [512 d][32 s] bf16, 32KB
  char* Psc = smem + 40960;                          // [64 q][32 s] bf16, 4KB
  unsigned short* Ps = (unsigned short*)Psc;
  float* Ls = (float*)(smem + 45056);                // [64] row sums

  const int tid = threadIdx.x;
  const int w = tid >> 6, lane = tid & 63, lr = lane & 15, g = lane >> 4;
  const int b = blockIdx.x >> 6, q0 = (blockIdx.x & 63) * QBLK;

  // Q A-fragments for this wave's 16 S-rows (KD=128 -> 4 chunks of 32)
  bf16x8 qf[4];
  {
    const unsigned short* qp = Qn + ((size_t)(b * LL + q0 + w * 16 + lr)) * KDIM + g * 8;
    #pragma unroll
    for (int kc = 0; kc < 4; ++kc)
      qf[kc] = *reinterpret_cast<const bf16x8*>(qp + kc * 32);
  }

  f32x4 acc[4][8];
  #pragma unroll
  for (int qt = 0; qt < 4; ++qt)
    #pragma unroll
    for (int ch = 0; ch < 8; ++ch) acc[qt][ch] = f32x4{0.f, 0.f, 0.f, 0.f};
  f32x4 lsum = f32x4{0.f, 0.f, 0.f, 0.f};

  for (int kt = 0; kt < NIT; ++kt) {
    if (kt) __syncthreads();
    // ---- stage K tile [32][128] ----
    #pragma unroll
    for (int p = 0; p < 2; ++p) {
      int j = tid + p * 256;
      int row = j >> 4, e0 = (j & 15) * 8;
      u16x8 v = *reinterpret_cast<const u16x8*>(
          Kn + ((size_t)(b * LL + kt * KBLK + row)) * KDIM + e0);
      *reinterpret_cast<u16x8*>(Ks + row * 256 + ((e0 * 2) ^ ((row & 7) << 4))) = v;
    }
    // ---- stage V^T tile [512][32] ----
    #pragma unroll 4
    for (int p = 0; p < 8; ++p) {
      int j = tid + p * 256;
      int d = j >> 2, s0 = (j & 3) * 8;
      u16x8 v = *reinterpret_cast<const u16x8*>(
          Vt + ((size_t)(b * DD + d)) * LL + kt * KBLK + s0);
      *reinterpret_cast<u16x8*>(Vs + d * 64 + ((s0 * 2) ^ (((d >> 1) & 3) << 4))) = v;
    }
    __syncthreads();

    // ---- S phase: 16 q x 32 s ----
    f32x4 sacc[2];
    #pragma unroll
    for (int ch = 0; ch < 2; ++ch) {
      sacc[ch] = f32x4{0.f, 0.f, 0.f, 0.f};
      int s = ch * 16 + lr;
      #pragma unroll
      for (int kc = 0; kc < 4; ++kc) {
        int o = (kc * 64 + g * 16) ^ ((s & 7) << 4);
        bf16x8 kb = *reinterpret_cast<const bf16x8*>(Ks + s * 256 + o);
        sacc[ch] = MFMA16(qf[kc], kb, sacc[ch]);
      }
    }
    // softmax numerator (fixed max 31) + P write
    #pragma unroll
    for (int ch = 0; ch < 2; ++ch) {
      #pragma unroll
      for (int i = 0; i < 4; ++i) {
        float p = exp2f(fmaf(sacc[ch][i], 43.280851f, -44.723546f));
        lsum[i] += p;
        int q = w * 16 + g * 4 + i;
        int idx = q * 32 + ((ch * 16 + lr) ^ (((q >> 1) & 3) << 3));
        Ps[idx] = f2bf(p);
      }
    }
    __syncthreads();

    // ---- PV phase: all 64 q x this wave's 128-wide D slice ----
    bf16x8 vb[8];
    #pragma unroll
    for (int ch = 0; ch < 8; ++ch) {
      int d = w * 128 + ch * 16 + lr;
      vb[ch] = *reinterpret_cast<const bf16x8*>(
          Vs + d * 64 + ((g * 16) ^ (((d >> 1) & 3) << 4)));
    }
    #pragma unroll
    for (int qt = 0; qt < 4; ++qt) {
      int q = qt * 16 + lr;
      bf16x8 pa = *reinterpret_cast<const bf16x8*>(
          Psc + q * 64 + ((g * 16) ^ (((q >> 1) & 3) << 4)));
      #pragma unroll
      for (int ch = 0; ch < 8; ++ch) acc[qt][ch] = MFMA16(pa, vb[ch], acc[qt][ch]);
    }
  }

  // ---- row-sum reduce across the 16-lane col groups ----
  #pragma unroll
  for (int m = 1; m < 16; m <<= 1) {
    #pragma unroll
    for (int i = 0; i < 4; ++i) lsum[i] += __shfl_xor(lsum[i], m);
  }
  if (lr == 0) {
    #pragma unroll
    for (int i = 0; i < 4; ++i) Ls[w * 16 + g * 4 + i] = lsum[i];
  }
  __syncthreads();

  // ---- scale by 1/l and store ----
  #pragma unroll
  for (int qt = 0; qt < 4; ++qt) {
    float linv[4];
    #pragma unroll
    for (int i = 0; i < 4; ++i) linv[i] = 1.0f / Ls[qt * 16 + g * 4 + i];
    #pragma unroll
    for (int ch = 0; ch < 8; ++ch) {
      int d = w * 128 + ch * 16 + lr;
      #pragma unroll
      for (int i = 0; i < 4; ++i) {
        int q = q0 + qt * 16 + g * 4 + i;
        Out[((size_t)(q * NB + b)) * DD + d] = acc[qt][ch][i] * linv[i];
      }
    }
  }
}

// ==========================================================================
extern "C" void kernel_launch(void* const* d_in, const int* in_sizes, int n_in,
                              void* d_out, int out_size, void* d_ws, size_t ws_size,
                              hipStream_t stream) {
  const float* query = (const float*)d_in[0];
  const float* key   = (const float*)d_in[1];
  const float* value = (const float*)d_in[2];
  const float* WKw   = (const float*)d_in[3];
  const float* WKb   = (const float*)d_in[4];
  const float* WVw   = (const float*)d_in[5];
  const float* WVb   = (const float*)d_in[6];
  float* out = (float*)d_out;

  unsigned short* wqn = (unsigned short*)d_ws;            // [4][4096][128] bf16
  unsigned short* wkn = wqn + (size_t)NB * LL * KDIM;     // [4][4096][128] bf16
  unsigned short* vt  = wkn + (size_t)NB * LL * KDIM;     // [4][512][4096] bf16

  proj_qk_kernel<<<256, 256, 0, stream>>>(query, WKw, WKb, wqn);
  proj_qk_kernel<<<256, 256, 0, stream>>>(key,   WKw, WKb, wkn);
  proj_v_kernel <<<512, 256, 0, stream>>>(value, WVw, WVb, vt);
  attn_kernel   <<<256, 256, 0, stream>>>(wqn, wkn, vt, out);
}

// Round 2
// 241.247 us; speedup vs baseline: 1.4276x; 1.4276x over previous
//
#include <hip/hip_runtime.h>

// ---------- types ----------
using bf16x8 = __attribute__((ext_vector_type(8))) short;           // 8 bf16 (4 VGPR)
using u16x8  = __attribute__((ext_vector_type(8))) unsigned short;  // 16B staging
using f32x4  = __attribute__((ext_vector_type(4))) float;
using f32x4v = __attribute__((ext_vector_type(4))) float;

__device__ inline unsigned short f2bf(float f) {
  unsigned int u = __builtin_bit_cast(unsigned int, f);
  return (unsigned short)((u + 0x7fffu + ((u >> 16) & 1u)) >> 16);  // RNE
}

#define MFMA16(a, b, c) __builtin_amdgcn_mfma_f32_16x16x32_bf16((a), (b), (c), 0, 0, 0)

// Problem constants
#define LL 4096
#define NB 4
#define DD 512
#define KDIM 128

// ==========================================================================
// proj_qk: Out[b][l][128] = bf16( l2norm( X[l][b][:] @ Wk^T + bk ) )
// ==========================================================================
__global__ __launch_bounds__(256) void proj_qk_kernel(
    const float* __restrict__ X, const float* __restrict__ Wk,
    const float* __restrict__ bk, unsigned short* __restrict__ Out)
{
  __shared__ char smem[49152];                       // Xs 16KB | Ws 32KB
  char* Xs = smem;
  char* Ws = smem + 16384;

  const int tid = threadIdx.x;
  const int w = tid >> 6, lane = tid & 63, lr = lane & 15, g = lane >> 4;
  const int r0 = blockIdx.x * 64;

  f32x4 acc[8];
  #pragma unroll
  for (int nt = 0; nt < 8; ++nt) acc[nt] = f32x4{0.f, 0.f, 0.f, 0.f};

  for (int kc = 0; kc < 4; ++kc) {                   // K chunks of 128
    if (kc) __syncthreads();
    #pragma unroll
    for (int p = 0; p < 4; ++p) {
      int j = tid + p * 256;
      int row = j >> 4, e0 = (j & 15) * 8;
      const float* src = X + (size_t)(r0 + row) * DD + kc * 128 + e0;
      f32x4v f0 = *reinterpret_cast<const f32x4v*>(src);
      f32x4v f1 = *reinterpret_cast<const f32x4v*>(src + 4);
      u16x8 v;
      #pragma unroll
      for (int e = 0; e < 4; ++e) { v[e] = f2bf(f0[e]); v[e + 4] = f2bf(f1[e]); }
      *reinterpret_cast<u16x8*>(Xs + row * 256 + ((e0 * 2) ^ ((row & 7) << 4))) = v;
    }
    #pragma unroll
    for (int p = 0; p < 8; ++p) {
      int j = tid + p * 256;
      int n = j >> 4, e0 = (j & 15) * 8;
      const float* src = Wk + (size_t)n * DD + kc * 128 + e0;
      f32x4v f0 = *reinterpret_cast<const f32x4v*>(src);
      f32x4v f1 = *reinterpret_cast<const f32x4v*>(src + 4);
      u16x8 v;
      #pragma unroll
      for (int e = 0; e < 4; ++e) { v[e] = f2bf(f0[e]); v[e + 4] = f2bf(f1[e]); }
      *reinterpret_cast<u16x8*>(Ws + n * 256 + ((e0 * 2) ^ ((n & 7) << 4))) = v;
    }
    __syncthreads();
    const int arow = w * 16 + lr;
    #pragma unroll
    for (int ks = 0; ks < 4; ++ks) {
      int oa = (ks * 64 + g * 16) ^ ((arow & 7) << 4);
      bf16x8 a = *reinterpret_cast<const bf16x8*>(Xs + arow * 256 + oa);
      #pragma unroll
      for (int nt = 0; nt < 8; ++nt) {
        int n = nt * 16 + lr;
        int ob = (ks * 64 + g * 16) ^ ((n & 7) << 4);
        bf16x8 bb = *reinterpret_cast<const bf16x8*>(Ws + n * 256 + ob);
        acc[nt] = MFMA16(a, bb, acc[nt]);
      }
    }
  }

  float bias[8];
  #pragma unroll
  for (int nt = 0; nt < 8; ++nt) bias[nt] = bk[nt * 16 + lr];
  #pragma unroll
  for (int nt = 0; nt < 8; ++nt)
    #pragma unroll
    for (int i = 0; i < 4; ++i) acc[nt][i] += bias[nt];

  f32x4 ss = f32x4{0.f, 0.f, 0.f, 0.f};
  #pragma unroll
  for (int nt = 0; nt < 8; ++nt)
    #pragma unroll
    for (int i = 0; i < 4; ++i) ss[i] += acc[nt][i] * acc[nt][i];
  #pragma unroll
  for (int m = 1; m < 16; m <<= 1) {
    #pragma unroll
    for (int i = 0; i < 4; ++i) ss[i] += __shfl_xor(ss[i], m);
  }
  float inv[4];
  #pragma unroll
  for (int i = 0; i < 4; ++i) inv[i] = 1.0f / fmaxf(sqrtf(ss[i]), 1e-12f);

  #pragma unroll
  for (int nt = 0; nt < 8; ++nt) {
    int c = nt * 16 + lr;
    #pragma unroll
    for (int i = 0; i < 4; ++i) {
      int r = r0 + w * 16 + g * 4 + i;
      int l = r >> 2, b = r & 3;
      Out[((size_t)(b * LL + l)) * KDIM + c] = f2bf(acc[nt][i] * inv[i]);
    }
  }
}

// ==========================================================================
// proj_v: Vt[b][d][s] = bf16( value[s][b][:] @ Wv^T + bv )   (transposed store)
// ==========================================================================
__global__ __launch_bounds__(256) void proj_v_kernel(
    const float* __restrict__ X, const float* __restrict__ Wv,
    const float* __restrict__ bv, unsigned short* __restrict__ VtOut)
{
  __shared__ char smem[40960];
  char* Xs = smem;
  char* Ws = smem + 32768;

  const int tid = threadIdx.x;
  const int w = tid >> 6, lane = tid & 63, lr = lane & 15, g = lane >> 4;
  const int rb = blockIdx.x >> 3, nb = blockIdx.x & 7;
  const int r0 = rb * 256, d0 = nb * 64;

  f32x4 acc[4][4];
  #pragma unroll
  for (int rt = 0; rt < 4; ++rt)
    #pragma unroll
    for (int nt = 0; nt < 4; ++nt) acc[rt][nt] = f32x4{0.f, 0.f, 0.f, 0.f};

  for (int kc = 0; kc < 8; ++kc) {
    if (kc) __syncthreads();
    #pragma unroll
    for (int p = 0; p < 8; ++p) {
      int j = tid + p * 256;
      int row = j >> 3, e0 = (j & 7) * 8;
      const float* src = X + (size_t)(r0 + row) * DD + kc * 64 + e0;
      f32x4v f0 = *reinterpret_cast<const f32x4v*>(src);
      f32x4v f1 = *reinterpret_cast<const f32x4v*>(src + 4);
      u16x8 v;
      #pragma unroll
      for (int e = 0; e < 4; ++e) { v[e] = f2bf(f0[e]); v[e + 4] = f2bf(f1[e]); }
      *reinterpret_cast<u16x8*>(Xs + row * 128 + ((e0 * 2) ^ ((row & 7) << 4))) = v;
    }
    #pragma unroll
    for (int p = 0; p < 2; ++p) {
      int j = tid + p * 256;
      int n = j >> 3, e0 = (j & 7) * 8;
      const float* src = Wv + (size_t)(d0 + n) * DD + kc * 64 + e0;
      f32x4v f0 = *reinterpret_cast<const f32x4v*>(src);
      f32x4v f1 = *reinterpret_cast<const f32x4v*>(src + 4);
      u16x8 v;
      #pragma unroll
      for (int e = 0; e < 4; ++e) { v[e] = f2bf(f0[e]); v[e + 4] = f2bf(f1[e]); }
      *reinterpret_cast<u16x8*>(Ws + n * 128 + ((e0 * 2) ^ ((n & 7) << 4))) = v;
    }
    __syncthreads();
    #pragma unroll
    for (int ks = 0; ks < 2; ++ks) {
      bf16x8 a[4];
      #pragma unroll
      for (int rt = 0; rt < 4; ++rt) {
        int arow = w * 64 + rt * 16 + lr;
        a[rt] = *reinterpret_cast<const bf16x8*>(
            Xs + arow * 128 + ((ks * 64 + g * 16) ^ ((arow & 7) << 4)));
      }
      #pragma unroll
      for (int nt = 0; nt < 4; ++nt) {
        int n = nt * 16 + lr;
        bf16x8 bb = *reinterpret_cast<const bf16x8*>(
            Ws + n * 128 + ((ks * 64 + g * 16) ^ ((n & 7) << 4)));
        #pragma unroll
        for (int rt = 0; rt < 4; ++rt) acc[rt][nt] = MFMA16(a[rt], bb, acc[rt][nt]);
      }
    }
  }

  __syncthreads();
  float bias[4];
  #pragma unroll
  for (int nt = 0; nt < 4; ++nt) bias[nt] = bv[d0 + nt * 16 + lr];

  unsigned short* Ts = (unsigned short*)smem;
  #pragma unroll
  for (int rt = 0; rt < 4; ++rt)
    #pragma unroll
    for (int nt = 0; nt < 4; ++nt) {
      int dl = nt * 16 + lr;
      #pragma unroll
      for (int i = 0; i < 4; ++i) {
        int rl = w * 64 + rt * 16 + g * 4 + i;
        Ts[dl * 256 + (rl ^ ((dl & 31) << 1))] = f2bf(acc[rt][nt][i] + bias[nt]);
      }
    }
  __syncthreads();

  int bsel = tid >> 6, dl = tid & 63;
  int l0 = r0 >> 2;
  #pragma unroll
  for (int jj = 0; jj < 8; ++jj) {
    u16x8 v;
    #pragma unroll
    for (int e = 0; e < 8; ++e) {
      int rl = (jj * 8 + e) * 4 + bsel;
      v[e] = Ts[dl * 256 + (rl ^ ((dl & 31) << 1))];
    }
    *reinterpret_cast<u16x8*>(VtOut + ((size_t)(bsel * DD + d0 + dl)) * LL + l0 + jj * 8) = v;
  }
}

// ==========================================================================
// attn v2: 512 thr / 8 waves, QBLK=64, KBLK=64, 1 barrier per step.
// Wave w = (wq = w&3, ws = w>>2): S-subtile q[wq*16..+16) x s[ws*32..+32).
// PV: all 64 q x d-slice [w*64..+64), V prefetched straight to regs (no LDS).
// K tile + P tile double-buffered in LDS.
// ==========================================================================
#define QBLK 64
#define KBLK 64
#define NIT2 (LL / KBLK)          // 64 steps

__device__ __forceinline__ void attn_step(
    int kt1, const unsigned short* __restrict__ Kp,
    const unsigned short* __restrict__ Vp,
    const char* kcur, char* knxt, char* pcur,
    const bf16x8 (&qf)[4], bf16x8 (&vcur)[8], bf16x8 (&vnxt)[8],
    f32x4 (&acc)[4][4], float (&lsum)[4],
    int lr, int g, int w, int wq, int ws, int r0k, int c0k)
{
  // ---- prefetch K(t+1) -> regs (issued first: oldest vmcnt) ----
  u16x8 kpr0 = *reinterpret_cast<const u16x8*>(
      Kp + (size_t)(kt1 * KBLK + r0k) * KDIM + c0k);
  u16x8 kpr1 = *reinterpret_cast<const u16x8*>(
      Kp + (size_t)(kt1 * KBLK + r0k + 32) * KDIM + c0k);
  // ---- prefetch V(t+1) -> regs ----
  #pragma unroll
  for (int u = 0; u < 8; ++u) {
    int ks = u >> 2, ch = u & 3;
    vnxt[u] = *reinterpret_cast<const bf16x8*>(
        Vp + (size_t)(w * 64 + ch * 16 + lr) * LL + kt1 * KBLK + ks * 32 + g * 8);
  }

  // ---- S phase: 16 q x 32 s from Ks[cur] ----
  f32x4 s0 = f32x4{0.f, 0.f, 0.f, 0.f};
  f32x4 s1 = f32x4{0.f, 0.f, 0.f, 0.f};
  const int sr0 = ws * 32 + lr, sr1 = sr0 + 16;
  #pragma unroll
  for (int kc = 0; kc < 4; ++kc) {
    bf16x8 kb0 = *reinterpret_cast<const bf16x8*>(
        kcur + sr0 * 256 + ((kc * 64 + g * 16) ^ ((sr0 & 7) << 4)));
    bf16x8 kb1 = *reinterpret_cast<const bf16x8*>(
        kcur + sr1 * 256 + ((kc * 64 + g * 16) ^ ((sr1 & 7) << 4)));
    s0 = MFMA16(qf[kc], kb0, s0);
    s1 = MFMA16(qf[kc], kb1, s1);
  }

  // ---- softmax numerator (fixed max 31) + P write ----
  #pragma unroll
  for (int i = 0; i < 4; ++i) {
    float p0 = exp2f(fmaf(s0[i], 43.280851f, -44.723546f));
    float p1 = exp2f(fmaf(s1[i], 43.280851f, -44.723546f));
    lsum[i] += p0 + p1;
    int q = wq * 16 + g * 4 + i;
    int swz = (q & 7) << 4;
    *(unsigned short*)(pcur + q * 128 + ((sr0 * 2) ^ swz)) = f2bf(p0);
    *(unsigned short*)(pcur + q * 128 + ((sr1 * 2) ^ swz)) = f2bf(p1);
  }

  // ---- write K(t+1) regs -> other LDS buffer ----
  {
    int swz = (r0k & 7) << 4;
    *reinterpret_cast<u16x8*>(knxt + r0k * 256 + ((c0k * 2) ^ swz)) = kpr0;
    *reinterpret_cast<u16x8*>(knxt + (r0k + 32) * 256 + ((c0k * 2) ^ swz)) = kpr1;
  }

  __syncthreads();   // P(t) ready, K(t+1) ready, buffers recycled safely

  // ---- PV phase: all 64 q x this wave's 64-wide d slice ----
  #pragma unroll
  for (int qt = 0; qt < 4; ++qt) {
    int q = qt * 16 + lr;
    int swz = (q & 7) << 4;
    bf16x8 pa0 = *reinterpret_cast<const bf16x8*>(pcur + q * 128 + ((g * 16) ^ swz));
    bf16x8 pa1 = *reinterpret_cast<const bf16x8*>(pcur + q * 128 + ((64 + g * 16) ^ swz));
    #pragma unroll
    for (int ch = 0; ch < 4; ++ch) {
      acc[qt][ch] = MFMA16(pa0, vcur[ch], acc[qt][ch]);
      acc[qt][ch] = MFMA16(pa1, vcur[4 + ch], acc[qt][ch]);
    }
  }
}

__global__ __launch_bounds__(512, 2) void attn_kernel(
    const unsigned short* __restrict__ Qn, const unsigned short* __restrict__ Kn,
    const unsigned short* __restrict__ Vt, float* __restrict__ Out)
{
  __shared__ char smem[49664];
  char* Ks0 = smem;                                  // [64 s][128 k] bf16, 16KB
  char* Ks1 = smem + 16384;
  char* Ps0 = smem + 32768;                          // [64 q][64 s] bf16, 8KB
  char* Ps1 = smem + 40960;
  float* Ls = (float*)(smem + 49152);                // [2][64] partial row sums

  const int tid = threadIdx.x;
  const int w = tid >> 6, lane = tid & 63, lr = lane & 15, g = lane >> 4;
  const int wq = w & 3, ws = w >> 2;
  const int r0k = tid >> 4, c0k = (tid & 15) * 8;    // K staging mapping

  // XCD-grouping swizzle: batch b -> XCD pair {2b, 2b+1} (assumes rr dispatch)
  const int bid = blockIdx.x;
  const int b = (bid & 7) >> 1;
  const int tile = ((bid >> 3) << 1) | (bid & 1);
  const int q0 = tile * QBLK;

  const unsigned short* Kp = Kn + (size_t)b * LL * KDIM;
  const unsigned short* Vp = Vt + (size_t)b * DD * LL;

  // Q A-fragments (KD=128 -> 4 chunks of 32)
  bf16x8 qf[4];
  {
    const unsigned short* qp = Qn + ((size_t)(b * LL + q0 + wq * 16 + lr)) * KDIM + g * 8;
    #pragma unroll
    for (int kc = 0; kc < 4; ++kc)
      qf[kc] = *reinterpret_cast<const bf16x8*>(qp + kc * 32);
  }

  f32x4 acc[4][4];
  #pragma unroll
  for (int qt = 0; qt < 4; ++qt)
    #pragma unroll
    for (int ch = 0; ch < 4; ++ch) acc[qt][ch] = f32x4{0.f, 0.f, 0.f, 0.f};
  float lsum[4] = {0.f, 0.f, 0.f, 0.f};

  bf16x8 vbA[8], vbB[8];

  // ---- prologue: K(0) -> Ks0, V(0) -> vbA ----
  {
    u16x8 k0 = *reinterpret_cast<const u16x8*>(Kp + (size_t)r0k * KDIM + c0k);
    u16x8 k1 = *reinterpret_cast<const u16x8*>(Kp + (size_t)(r0k + 32) * KDIM + c0k);
    int swz = (r0k & 7) << 4;
    *reinterpret_cast<u16x8*>(Ks0 + r0k * 256 + ((c0k * 2) ^ swz)) = k0;
    *reinterpret_cast<u16x8*>(Ks0 + (r0k + 32) * 256 + ((c0k * 2) ^ swz)) = k1;
    #pragma unroll
    for (int u = 0; u < 8; ++u) {
      int ks = u >> 2, ch = u & 3;
      vbA[u] = *reinterpret_cast<const bf16x8*>(
          Vp + (size_t)(w * 64 + ch * 16 + lr) * LL + ks * 32 + g * 8);
    }
  }
  __syncthreads();

  // ---- main loop, 2 steps per iter (static buffer/reg naming) ----
  for (int t = 0; t < NIT2; t += 2) {
    int k1i = (t + 1 < NIT2) ? t + 1 : NIT2 - 1;
    int k2i = (t + 2 < NIT2) ? t + 2 : NIT2 - 1;
    attn_step(k1i, Kp, Vp, Ks0, Ks1, Ps0, qf, vbA, vbB, acc, lsum,
              lr, g, w, wq, ws, r0k, c0k);
    attn_step(k2i, Kp, Vp, Ks1, Ks0, Ps1, qf, vbB, vbA, acc, lsum,
              lr, g, w, wq, ws, r0k, c0k);
  }

  // ---- combine partial row sums across the two s-halves ----
  #pragma unroll
  for (int m = 1; m < 16; m <<= 1) {
    #pragma unroll
    for (int i = 0; i < 4; ++i) lsum[i] += __shfl_xor(lsum[i], m);
  }
  if (lr == 0) {
    #pragma unroll
    for (int i = 0; i < 4; ++i) Ls[ws * 64 + wq * 16 + g * 4 + i] = lsum[i];
  }
  __syncthreads();

  // ---- scale by 1/l and store ----
  #pragma unroll
  for (int qt = 0; qt < 4; ++qt) {
    float linv[4];
    #pragma unroll
    for (int i = 0; i < 4; ++i) {
      int q = qt * 16 + g * 4 + i;
      linv[i] = 1.0f / (Ls[q] + Ls[64 + q]);
    }
    #pragma unroll
    for (int ch = 0; ch < 4; ++ch) {
      int d = w * 64 + ch * 16 + lr;
      #pragma unroll
      for (int i = 0; i < 4; ++i) {
        int q = q0 + qt * 16 + g * 4 + i;
        Out[((size_t)q * NB + b) * DD + d] = acc[qt][ch][i] * linv[i];
      }
    }
  }
}

// ==========================================================================
extern "C" void kernel_launch(void* const* d_in, const int* in_sizes, int n_in,
                              void* d_out, int out_size, void* d_ws, size_t ws_size,
                              hipStream_t stream) {
  const float* query = (const float*)d_in[0];
  const float* key   = (const float*)d_in[1];
  const float* value = (const float*)d_in[2];
  const float* WKw   = (const float*)d_in[3];
  const float* WKb   = (const float*)d_in[4];
  const float* WVw   = (const float*)d_in[5];
  const float* WVb   = (const float*)d_in[6];
  float* out = (float*)d_out;

  unsigned short* wqn = (unsigned short*)d_ws;            // [4][4096][128] bf16
  unsigned short* wkn = wqn + (size_t)NB * LL * KDIM;     // [4][4096][128] bf16
  unsigned short* vt  = wkn + (size_t)NB * LL * KDIM;     // [4][512][4096] bf16

  proj_qk_kernel<<<256, 256, 0, stream>>>(query, WKw, WKb, wqn);
  proj_qk_kernel<<<256, 256, 0, stream>>>(key,   WKw, WKb, wkn);
  proj_v_kernel <<<512, 256, 0, stream>>>(value, WVw, WVb, vt);
  attn_kernel   <<<256, 512, 0, stream>>>(wqn, wkn, vt, out);
}

// Round 3
// 224.067 us; speedup vs baseline: 1.5371x; 1.0767x over previous
//
#include <hip/hip_runtime.h>

// ---------- types ----------
using bf16x8 = __attribute__((ext_vector_type(8))) short;           // 8 bf16 (4 VGPR)
using u16x8  = __attribute__((ext_vector_type(8))) unsigned short;  // 16B staging
using f32x4  = __attribute__((ext_vector_type(4))) float;
using f32x4v = __attribute__((ext_vector_type(4))) float;

__device__ inline unsigned short f2bf(float f) {
  unsigned int u = __builtin_bit_cast(unsigned int, f);
  return (unsigned short)((u + 0x7fffu + ((u >> 16) & 1u)) >> 16);  // RNE
}

#define MFMA16(a, b, c) __builtin_amdgcn_mfma_f32_16x16x32_bf16((a), (b), (c), 0, 0, 0)

// Manual barrier: LDS-visibility only. Does NOT drain vmcnt -> global-load
// prefetches legally stay in flight across the barrier (all cross-thread
// communication in the loop is through LDS; buffers are recycled only after
// one further barrier, and lgkmcnt(0) drains both ds_read and ds_write).
__device__ __forceinline__ void lds_barrier() {
  __builtin_amdgcn_sched_barrier(0);
  asm volatile("s_waitcnt lgkmcnt(0)" ::: "memory");
  __builtin_amdgcn_sched_barrier(0);
  __builtin_amdgcn_s_barrier();
  __builtin_amdgcn_sched_barrier(0);
}

// Problem constants
#define LL 4096
#define NB 4
#define DD 512
#define KDIM 128

// ==========================================================================
// proj_qk (merged q+k): Out[b][l][128] = bf16( l2norm( X[l][b][:] @ Wk^T + bk ) )
// grid 512: bid&1 selects {query,key}; r0 = (bid>>1)*64 -> 2 blocks/CU.
// ==========================================================================
__global__ __launch_bounds__(256) void proj_qk_kernel(
    const float* __restrict__ Xq, const float* __restrict__ Xk,
    const float* __restrict__ Wk, const float* __restrict__ bk,
    unsigned short* __restrict__ Outq, unsigned short* __restrict__ Outk)
{
  __shared__ char smem[49152];                       // Xs 16KB | Ws 32KB
  char* Xs = smem;
  char* Ws = smem + 16384;

  const int tid = threadIdx.x;
  const int w = tid >> 6, lane = tid & 63, lr = lane & 15, g = lane >> 4;
  const int sel = blockIdx.x & 1;
  const float* X = sel ? Xk : Xq;
  unsigned short* Out = sel ? Outk : Outq;
  const int r0 = (blockIdx.x >> 1) * 64;

  f32x4 acc[8];
  #pragma unroll
  for (int nt = 0; nt < 8; ++nt) acc[nt] = f32x4{0.f, 0.f, 0.f, 0.f};

  for (int kc = 0; kc < 4; ++kc) {                   // K chunks of 128
    if (kc) __syncthreads();
    #pragma unroll
    for (int p = 0; p < 4; ++p) {
      int j = tid + p * 256;
      int row = j >> 4, e0 = (j & 15) * 8;
      const float* src = X + (size_t)(r0 + row) * DD + kc * 128 + e0;
      f32x4v f0 = *reinterpret_cast<const f32x4v*>(src);
      f32x4v f1 = *reinterpret_cast<const f32x4v*>(src + 4);
      u16x8 v;
      #pragma unroll
      for (int e = 0; e < 4; ++e) { v[e] = f2bf(f0[e]); v[e + 4] = f2bf(f1[e]); }
      *reinterpret_cast<u16x8*>(Xs + row * 256 + ((e0 * 2) ^ ((row & 7) << 4))) = v;
    }
    #pragma unroll
    for (int p = 0; p < 8; ++p) {
      int j = tid + p * 256;
      int n = j >> 4, e0 = (j & 15) * 8;
      const float* src = Wk + (size_t)n * DD + kc * 128 + e0;
      f32x4v f0 = *reinterpret_cast<const f32x4v*>(src);
      f32x4v f1 = *reinterpret_cast<const f32x4v*>(src + 4);
      u16x8 v;
      #pragma unroll
      for (int e = 0; e < 4; ++e) { v[e] = f2bf(f0[e]); v[e + 4] = f2bf(f1[e]); }
      *reinterpret_cast<u16x8*>(Ws + n * 256 + ((e0 * 2) ^ ((n & 7) << 4))) = v;
    }
    __syncthreads();
    const int arow = w * 16 + lr;
    #pragma unroll
    for (int ks = 0; ks < 4; ++ks) {
      int oa = (ks * 64 + g * 16) ^ ((arow & 7) << 4);
      bf16x8 a = *reinterpret_cast<const bf16x8*>(Xs + arow * 256 + oa);
      #pragma unroll
      for (int nt = 0; nt < 8; ++nt) {
        int n = nt * 16 + lr;
        int ob = (ks * 64 + g * 16) ^ ((n & 7) << 4);
        bf16x8 bb = *reinterpret_cast<const bf16x8*>(Ws + n * 256 + ob);
        acc[nt] = MFMA16(a, bb, acc[nt]);
      }
    }
  }

  float bias[8];
  #pragma unroll
  for (int nt = 0; nt < 8; ++nt) bias[nt] = bk[nt * 16 + lr];
  #pragma unroll
  for (int nt = 0; nt < 8; ++nt)
    #pragma unroll
    for (int i = 0; i < 4; ++i) acc[nt][i] += bias[nt];

  f32x4 ss = f32x4{0.f, 0.f, 0.f, 0.f};
  #pragma unroll
  for (int nt = 0; nt < 8; ++nt)
    #pragma unroll
    for (int i = 0; i < 4; ++i) ss[i] += acc[nt][i] * acc[nt][i];
  #pragma unroll
  for (int m = 1; m < 16; m <<= 1) {
    #pragma unroll
    for (int i = 0; i < 4; ++i) ss[i] += __shfl_xor(ss[i], m);
  }
  float inv[4];
  #pragma unroll
  for (int i = 0; i < 4; ++i) inv[i] = 1.0f / fmaxf(sqrtf(ss[i]), 1e-12f);

  #pragma unroll
  for (int nt = 0; nt < 8; ++nt) {
    int c = nt * 16 + lr;
    #pragma unroll
    for (int i = 0; i < 4; ++i) {
      int r = r0 + w * 16 + g * 4 + i;
      int l = r >> 2, b = r & 3;
      Out[((size_t)(b * LL + l)) * KDIM + c] = f2bf(acc[nt][i] * inv[i]);
    }
  }
}

// ==========================================================================
// proj_v: Vt[b][d][s] = bf16( value[s][b][:] @ Wv^T + bv )   (transposed store)
// ==========================================================================
__global__ __launch_bounds__(256) void proj_v_kernel(
    const float* __restrict__ X, const float* __restrict__ Wv,
    const float* __restrict__ bv, unsigned short* __restrict__ VtOut)
{
  __shared__ char smem[40960];
  char* Xs = smem;
  char* Ws = smem + 32768;

  const int tid = threadIdx.x;
  const int w = tid >> 6, lane = tid & 63, lr = lane & 15, g = lane >> 4;
  const int rb = blockIdx.x >> 3, nb = blockIdx.x & 7;
  const int r0 = rb * 256, d0 = nb * 64;

  f32x4 acc[4][4];
  #pragma unroll
  for (int rt = 0; rt < 4; ++rt)
    #pragma unroll
    for (int nt = 0; nt < 4; ++nt) acc[rt][nt] = f32x4{0.f, 0.f, 0.f, 0.f};

  for (int kc = 0; kc < 8; ++kc) {
    if (kc) __syncthreads();
    #pragma unroll
    for (int p = 0; p < 8; ++p) {
      int j = tid + p * 256;
      int row = j >> 3, e0 = (j & 7) * 8;
      const float* src = X + (size_t)(r0 + row) * DD + kc * 64 + e0;
      f32x4v f0 = *reinterpret_cast<const f32x4v*>(src);
      f32x4v f1 = *reinterpret_cast<const f32x4v*>(src + 4);
      u16x8 v;
      #pragma unroll
      for (int e = 0; e < 4; ++e) { v[e] = f2bf(f0[e]); v[e + 4] = f2bf(f1[e]); }
      *reinterpret_cast<u16x8*>(Xs + row * 128 + ((e0 * 2) ^ ((row & 7) << 4))) = v;
    }
    #pragma unroll
    for (int p = 0; p < 2; ++p) {
      int j = tid + p * 256;
      int n = j >> 3, e0 = (j & 7) * 8;
      const float* src = Wv + (size_t)(d0 + n) * DD + kc * 64 + e0;
      f32x4v f0 = *reinterpret_cast<const f32x4v*>(src);
      f32x4v f1 = *reinterpret_cast<const f32x4v*>(src + 4);
      u16x8 v;
      #pragma unroll
      for (int e = 0; e < 4; ++e) { v[e] = f2bf(f0[e]); v[e + 4] = f2bf(f1[e]); }
      *reinterpret_cast<u16x8*>(Ws + n * 128 + ((e0 * 2) ^ ((n & 7) << 4))) = v;
    }
    __syncthreads();
    #pragma unroll
    for (int ks = 0; ks < 2; ++ks) {
      bf16x8 a[4];
      #pragma unroll
      for (int rt = 0; rt < 4; ++rt) {
        int arow = w * 64 + rt * 16 + lr;
        a[rt] = *reinterpret_cast<const bf16x8*>(
            Xs + arow * 128 + ((ks * 64 + g * 16) ^ ((arow & 7) << 4)));
      }
      #pragma unroll
      for (int nt = 0; nt < 4; ++nt) {
        int n = nt * 16 + lr;
        bf16x8 bb = *reinterpret_cast<const bf16x8*>(
            Ws + n * 128 + ((ks * 64 + g * 16) ^ ((n & 7) << 4)));
        #pragma unroll
        for (int rt = 0; rt < 4; ++rt) acc[rt][nt] = MFMA16(a[rt], bb, acc[rt][nt]);
      }
    }
  }

  __syncthreads();
  float bias[4];
  #pragma unroll
  for (int nt = 0; nt < 4; ++nt) bias[nt] = bv[d0 + nt * 16 + lr];

  unsigned short* Ts = (unsigned short*)smem;
  #pragma unroll
  for (int rt = 0; rt < 4; ++rt)
    #pragma unroll
    for (int nt = 0; nt < 4; ++nt) {
      int dl = nt * 16 + lr;
      #pragma unroll
      for (int i = 0; i < 4; ++i) {
        int rl = w * 64 + rt * 16 + g * 4 + i;
        Ts[dl * 256 + (rl ^ ((dl & 31) << 1))] = f2bf(acc[rt][nt][i] + bias[nt]);
      }
    }
  __syncthreads();

  int bsel = tid >> 6, dl = tid & 63;
  int l0 = r0 >> 2;
  #pragma unroll
  for (int jj = 0; jj < 8; ++jj) {
    u16x8 v;
    #pragma unroll
    for (int e = 0; e < 8; ++e) {
      int rl = (jj * 8 + e) * 4 + bsel;
      v[e] = Ts[dl * 256 + (rl ^ ((dl & 31) << 1))];
    }
    *reinterpret_cast<u16x8*>(VtOut + ((size_t)(bsel * DD + d0 + dl)) * LL + l0 + jj * 8) = v;
  }
}

// ==========================================================================
// attn v3: like v2 but the in-loop barrier drains lgkmcnt ONLY, so the
// K/V register prefetches issued in step t stay in flight across the
// barrier and land by their first use in step t+1 (compiler inserts the
// counted vmcnt waits from its own dependency tracking).
// ==========================================================================
#define QBLK 64
#define KBLK 64
#define NIT2 (LL / KBLK)          // 64 steps

__device__ __forceinline__ void attn_step(
    int kt1, const unsigned short* __restrict__ Kp,
    const unsigned short* __restrict__ Vp,
    const char* kcur, char* knxt, char* pcur,
    const bf16x8 (&qf)[4], bf16x8 (&vcur)[8], bf16x8 (&vnxt)[8],
    f32x4 (&acc)[4][4], float (&lsum)[4],
    int lr, int g, int w, int wq, int ws, int r0k, int c0k)
{
  // ---- prefetch K(t+1) -> regs (issued first: oldest vmcnt) ----
  u16x8 kpr0 = *reinterpret_cast<const u16x8*>(
      Kp + (size_t)(kt1 * KBLK + r0k) * KDIM + c0k);
  u16x8 kpr1 = *reinterpret_cast<const u16x8*>(
      Kp + (size_t)(kt1 * KBLK + r0k + 32) * KDIM + c0k);
  // ---- prefetch V(t+1) -> regs ----
  #pragma unroll
  for (int u = 0; u < 8; ++u) {
    int ks = u >> 2, ch = u & 3;
    vnxt[u] = *reinterpret_cast<const bf16x8*>(
        Vp + (size_t)(w * 64 + ch * 16 + lr) * LL + kt1 * KBLK + ks * 32 + g * 8);
  }

  // ---- S phase: 16 q x 32 s from Ks[cur] ----
  f32x4 s0 = f32x4{0.f, 0.f, 0.f, 0.f};
  f32x4 s1 = f32x4{0.f, 0.f, 0.f, 0.f};
  const int sr0 = ws * 32 + lr, sr1 = sr0 + 16;
  #pragma unroll
  for (int kc = 0; kc < 4; ++kc) {
    bf16x8 kb0 = *reinterpret_cast<const bf16x8*>(
        kcur + sr0 * 256 + ((kc * 64 + g * 16) ^ ((sr0 & 7) << 4)));
    bf16x8 kb1 = *reinterpret_cast<const bf16x8*>(
        kcur + sr1 * 256 + ((kc * 64 + g * 16) ^ ((sr1 & 7) << 4)));
    s0 = MFMA16(qf[kc], kb0, s0);
    s1 = MFMA16(qf[kc], kb1, s1);
  }

  // ---- softmax numerator (fixed max 31) + P write ----
  #pragma unroll
  for (int i = 0; i < 4; ++i) {
    float p0 = exp2f(fmaf(s0[i], 43.280851f, -44.723546f));
    float p1 = exp2f(fmaf(s1[i], 43.280851f, -44.723546f));
    lsum[i] += p0 + p1;
    int q = wq * 16 + g * 4 + i;
    int swz = (q & 7) << 4;
    *(unsigned short*)(pcur + q * 128 + ((sr0 * 2) ^ swz)) = f2bf(p0);
    *(unsigned short*)(pcur + q * 128 + ((sr1 * 2) ^ swz)) = f2bf(p1);
  }

  // ---- write K(t+1) regs -> other LDS buffer (waits vmcnt(8): V in flight) ----
  {
    int swz = (r0k & 7) << 4;
    *reinterpret_cast<u16x8*>(knxt + r0k * 256 + ((c0k * 2) ^ swz)) = kpr0;
    *reinterpret_cast<u16x8*>(knxt + (r0k + 32) * 256 + ((c0k * 2) ^ swz)) = kpr1;
  }

  lds_barrier();   // LDS-only drain; V prefetch stays in flight

  // ---- PV phase: all 64 q x this wave's 64-wide d slice ----
  #pragma unroll
  for (int qt = 0; qt < 4; ++qt) {
    int q = qt * 16 + lr;
    int swz = (q & 7) << 4;
    bf16x8 pa0 = *reinterpret_cast<const bf16x8*>(pcur + q * 128 + ((g * 16) ^ swz));
    bf16x8 pa1 = *reinterpret_cast<const bf16x8*>(pcur + q * 128 + ((64 + g * 16) ^ swz));
    #pragma unroll
    for (int ch = 0; ch < 4; ++ch) {
      acc[qt][ch] = MFMA16(pa0, vcur[ch], acc[qt][ch]);
      acc[qt][ch] = MFMA16(pa1, vcur[4 + ch], acc[qt][ch]);
    }
  }
}

__global__ __launch_bounds__(512, 2) void attn_kernel(
    const unsigned short* __restrict__ Qn, const unsigned short* __restrict__ Kn,
    const unsigned short* __restrict__ Vt, float* __restrict__ Out)
{
  __shared__ char smem[49664];
  char* Ks0 = smem;                                  // [64 s][128 k] bf16, 16KB
  char* Ks1 = smem + 16384;
  char* Ps0 = smem + 32768;                          // [64 q][64 s] bf16, 8KB
  char* Ps1 = smem + 40960;
  float* Ls = (float*)(smem + 49152);                // [2][64] partial row sums

  const int tid = threadIdx.x;
  const int w = tid >> 6, lane = tid & 63, lr = lane & 15, g = lane >> 4;
  const int wq = w & 3, ws = w >> 2;
  const int r0k = tid >> 4, c0k = (tid & 15) * 8;    // K staging mapping

  // XCD-grouping swizzle: batch b -> XCD pair {2b, 2b+1} (assumes rr dispatch)
  const int bid = blockIdx.x;
  const int b = (bid & 7) >> 1;
  const int tile = ((bid >> 3) << 1) | (bid & 1);
  const int q0 = tile * QBLK;

  const unsigned short* Kp = Kn + (size_t)b * LL * KDIM;
  const unsigned short* Vp = Vt + (size_t)b * DD * LL;

  // Q A-fragments (KD=128 -> 4 chunks of 32)
  bf16x8 qf[4];
  {
    const unsigned short* qp = Qn + ((size_t)(b * LL + q0 + wq * 16 + lr)) * KDIM + g * 8;
    #pragma unroll
    for (int kc = 0; kc < 4; ++kc)
      qf[kc] = *reinterpret_cast<const bf16x8*>(qp + kc * 32);
  }

  f32x4 acc[4][4];
  #pragma unroll
  for (int qt = 0; qt < 4; ++qt)
    #pragma unroll
    for (int ch = 0; ch < 4; ++ch) acc[qt][ch] = f32x4{0.f, 0.f, 0.f, 0.f};
  float lsum[4] = {0.f, 0.f, 0.f, 0.f};

  bf16x8 vbA[8], vbB[8];

  // ---- prologue: K(0) -> Ks0, V(0) -> vbA ----
  {
    u16x8 k0 = *reinterpret_cast<const u16x8*>(Kp + (size_t)r0k * KDIM + c0k);
    u16x8 k1 = *reinterpret_cast<const u16x8*>(Kp + (size_t)(r0k + 32) * KDIM + c0k);
    int swz = (r0k & 7) << 4;
    *reinterpret_cast<u16x8*>(Ks0 + r0k * 256 + ((c0k * 2) ^ swz)) = k0;
    *reinterpret_cast<u16x8*>(Ks0 + (r0k + 32) * 256 + ((c0k * 2) ^ swz)) = k1;
    #pragma unroll
    for (int u = 0; u < 8; ++u) {
      int ks = u >> 2, ch = u & 3;
      vbA[u] = *reinterpret_cast<const bf16x8*>(
          Vp + (size_t)(w * 64 + ch * 16 + lr) * LL + ks * 32 + g * 8);
    }
  }
  __syncthreads();

  // ---- main loop, 2 steps per iter (static buffer/reg naming) ----
  for (int t = 0; t < NIT2; t += 2) {
    int k1i = (t + 1 < NIT2) ? t + 1 : NIT2 - 1;
    int k2i = (t + 2 < NIT2) ? t + 2 : NIT2 - 1;
    attn_step(k1i, Kp, Vp, Ks0, Ks1, Ps0, qf, vbA, vbB, acc, lsum,
              lr, g, w, wq, ws, r0k, c0k);
    attn_step(k2i, Kp, Vp, Ks1, Ks0, Ps1, qf, vbB, vbA, acc, lsum,
              lr, g, w, wq, ws, r0k, c0k);
  }

  // ---- combine partial row sums across the two s-halves ----
  #pragma unroll
  for (int m = 1; m < 16; m <<= 1) {
    #pragma unroll
    for (int i = 0; i < 4; ++i) lsum[i] += __shfl_xor(lsum[i], m);
  }
  if (lr == 0) {
    #pragma unroll
    for (int i = 0; i < 4; ++i) Ls[ws * 64 + wq * 16 + g * 4 + i] = lsum[i];
  }
  __syncthreads();

  // ---- scale by 1/l and store ----
  #pragma unroll
  for (int qt = 0; qt < 4; ++qt) {
    float linv[4];
    #pragma unroll
    for (int i = 0; i < 4; ++i) {
      int q = qt * 16 + g * 4 + i;
      linv[i] = 1.0f / (Ls[q] + Ls[64 + q]);
    }
    #pragma unroll
    for (int ch = 0; ch < 4; ++ch) {
      int d = w * 64 + ch * 16 + lr;
      #pragma unroll
      for (int i = 0; i < 4; ++i) {
        int q = q0 + qt * 16 + g * 4 + i;
        Out[((size_t)q * NB + b) * DD + d] = acc[qt][ch][i] * linv[i];
      }
    }
  }
}

// ==========================================================================
extern "C" void kernel_launch(void* const* d_in, const int* in_sizes, int n_in,
                              void* d_out, int out_size, void* d_ws, size_t ws_size,
                              hipStream_t stream) {
  const float* query = (const float*)d_in[0];
  const float* key   = (const float*)d_in[1];
  const float* value = (const float*)d_in[2];
  const float* WKw   = (const float*)d_in[3];
  const float* WKb   = (const float*)d_in[4];
  const float* WVw   = (const float*)d_in[5];
  const float* WVb   = (const float*)d_in[6];
  float* out = (float*)d_out;

  unsigned short* wqn = (unsigned short*)d_ws;            // [4][4096][128] bf16
  unsigned short* wkn = wqn + (size_t)NB * LL * KDIM;     // [4][4096][128] bf16
  unsigned short* vt  = wkn + (size_t)NB * LL * KDIM;     // [4][512][4096] bf16

  proj_qk_kernel<<<512, 256, 0, stream>>>(query, key, WKw, WKb, wqn, wkn);
  proj_v_kernel <<<512, 256, 0, stream>>>(value, WVw, WVb, vt);
  attn_kernel   <<<256, 512, 0, stream>>>(wqn, wkn, vt, out);
}